// Round 20
// baseline (703.461 us; speedup 1.0000x reference)
//
#include <hip/hip_runtime.h>
#include <math.h>

#define NB   8
#define CI   64
#define COC  64
#define HQ   256
#define HK   64
#define KS   5
#define LL   256
#define NPAD 1664
#define QP2  (257 * 264)   // q bf16 plane (rows 0..256, row 256 = same-pad zeros)

typedef __attribute__((ext_vector_type(8))) short bf16x8s;
typedef __attribute__((ext_vector_type(4))) float f32x4;

static __device__ __forceinline__ unsigned short f2bf(float f) {
  union { float f; unsigned u; } v; v.f = f;
  unsigned r = v.u + 0x7FFF + ((v.u >> 16) & 1);
  return (unsigned short)(r >> 16);
}
static __device__ __forceinline__ float bf2f(unsigned short h) {
  union { unsigned u; float f; } v; v.u = ((unsigned)h) << 16; return v.f;
}

// ---------------- weight images for conv3m: 4 weights in one launch ----------------
// grid (18 ch, 4 w); wimg layout per weight: [18][64 co][40] bf16
__global__ void wtrans_mfma4(const float* __restrict__ W0, const float* __restrict__ W1,
                             const float* __restrict__ W2, const float* __restrict__ W3,
                             unsigned short* __restrict__ wimg) {
  const int ch = blockIdx.x, wsel = blockIdx.y;
  const float* Wt = (wsel == 0) ? W0 : (wsel == 1) ? W1 : (wsel == 2) ? W2 : W3;
  const int tap = ch >> 1, cih = ch & 1;
  unsigned short* dst = wimg + (size_t)wsel * 18 * 64 * 40 + (size_t)ch * 64 * 40;
  for (int idx = threadIdx.x; idx < 64 * 40; idx += 256) {
    const int co = idx / 40, s = idx - co * 40;
    unsigned short v = 0;
    if (s < 32) v = f2bf(Wt[((size_t)co * 64 + cih * 32 + s) * 9 + tap]);
    dst[idx] = v;
  }
}

// ---------------- pan fp32 [ci][256][256] -> bf16 [row 258][col 264][ci 64] ----------------
__global__ void pad_rci(const float* __restrict__ src, unsigned short* __restrict__ dst) {
  const int ct = blockIdx.x, g = blockIdx.y, n = blockIdx.z;
  const int c0 = ct * 66;
  __shared__ float t[64 * 68];
  const int jl = threadIdx.x & 63, cg = threadIdx.x >> 6;
  const int row = g - 1;
  const bool rok = (row >= 0 && row < 256);
  for (int ci = cg; ci < 64; ci += 4) {
    #pragma unroll
    for (int jb = 0; jb < 2; ++jb) {
      const int j = jl + jb * 64;
      if (j < 66) {
        const int x = c0 - 1 + j;
        float v = 0.f;
        if (rok && x >= 0 && x < 256)
          v = src[(((size_t)n * 64 + ci) * 256 + row) * 256 + x];
        t[ci * 68 + j] = v;
      }
    }
  }
  __syncthreads();
  const int cil = threadIdx.x & 63, cc = threadIdx.x >> 6;
  unsigned short* db = dst + (((size_t)n * 258 + g) * 264) * 64;
  for (int c = cc; c < 66; c += 4)
    db[(size_t)(c0 + c) * 64 + cil] = f2bf(t[cil * 68 + c]);
}

// ---------------- small fp32 [ci][64][64] -> bf16 [row 66][col 72][ci 64], 2 srcs ----------------
__global__ void pad_rci_s2(const float* __restrict__ s0, unsigned short* __restrict__ d0,
                           const float* __restrict__ s1, unsigned short* __restrict__ d1) {
  const int g = blockIdx.x;   // padded row 0..65
  const int n = blockIdx.y;
  const int sel = blockIdx.z;
  const float* src = sel ? s1 : s0;
  unsigned short* dst = sel ? d1 : d0;
  __shared__ float t[64 * 68];
  const int jl = threadIdx.x & 63, cg = threadIdx.x >> 6;
  const int row = g - 1;
  const bool rok = (row >= 0 && row < 64);
  for (int ci = cg; ci < 64; ci += 4) {
    #pragma unroll
    for (int jb = 0; jb < 2; ++jb) {
      const int j = jl + jb * 64;
      if (j < 66) {
        const int x = j - 1;
        float v = 0.f;
        if (rok && x >= 0 && x < 64)
          v = src[(((size_t)n * 64 + ci) * 64 + row) * 64 + x];
        t[ci * 68 + j] = v;
      }
    }
  }
  __syncthreads();
  const int cil = threadIdx.x & 63, cc = threadIdx.x >> 6;
  unsigned short* db = dst + ((size_t)n * 66 + g) * 72 * 64;
  for (int c = cc; c < 66; c += 4)
    db[(size_t)c * 64 + cil] = f2bf(t[cil * 68 + c]);
}

// zero borders of resbf ([258][264][64])
__global__ void rbz(unsigned short* __restrict__ resbf) {
  const int n = blockIdx.x;
  unsigned short* b = resbf + (size_t)n * 258 * 264 * 64;
  for (int idx = threadIdx.x; idx < 264 * 64; idx += 256) {
    b[idx] = 0;
    b[(size_t)257 * 264 * 64 + idx] = 0;
  }
  for (int idx = threadIdx.x; idx < 256 * 64; idx += 256) {
    const int r = idx >> 6, ci = idx & 63;
    b[((size_t)(r + 1) * 264) * 64 + ci] = 0;
    b[((size_t)(r + 1) * 264 + 257) * 64 + ci] = 0;
  }
}

// zero same-pad strips of q hi/lo ([257][264][64]): row 256 full, col 256 rows 0..255
__global__ void qz(unsigned short* __restrict__ qhi, unsigned short* __restrict__ qlo) {
  const int n = blockIdx.x;
  unsigned short* bh = qhi + (size_t)n * QP2 * 64;
  unsigned short* bl = qlo + (size_t)n * QP2 * 64;
  for (int g = threadIdx.x; g < 4224; g += 256) {
    ((unsigned long long*)(bh + (size_t)256 * 264 * 64))[g] = 0ull;
    ((unsigned long long*)(bl + (size_t)256 * 264 * 64))[g] = 0ull;
  }
  for (int g = threadIdx.x; g < 4096; g += 256) {
    const int r = g >> 4, q = g & 15;
    const size_t off = ((size_t)r * 264 + 256) * 64 + q * 4;
    *(unsigned long long*)(bh + off) = 0ull;
    *(unsigned long long*)(bl + off) = 0ull;
  }
}

// ---------------- MFMA conv 3x3 + bias + leaky relu, 2 rows/block (bf16 in, fp32 out) ----------------
__global__ __launch_bounds__(256) void conv3m(
    const unsigned short* __restrict__ inbf,
    const unsigned short* __restrict__ wimg,
    const float* __restrict__ bias,
    float* __restrict__ out, int PS, int RS, int inRS, long long inIS) {
  const int x0 = blockIdx.x * 64;
  const int y0 = blockIdx.y * 2;
  const int n  = blockIdx.z;
  const int tid = threadIdx.x;
  const int lane = tid & 63;
  const int wv = tid >> 6;
  const int col = lane & 15;
  const int kg  = lane >> 4;

  __shared__ unsigned short in_s[4 * 66 * 72];

  {
    const unsigned short* src = inbf + (size_t)n * inIS + (size_t)y0 * inRS;
    for (int pos = tid; pos < 264; pos += 256) {
      const int r = pos / 66, c = pos - r * 66;
      const unsigned short* s = src + (size_t)r * inRS + (size_t)(x0 + c) * 64;
      unsigned short* d = &in_s[pos * 72];
      #pragma unroll
      for (int q = 0; q < 8; ++q)
        *(float4*)(d + q * 8) = *(const float4*)(s + q * 8);
    }
  }
  __syncthreads();

  f32x4 acc[2][4];
  #pragma unroll
  for (int ry = 0; ry < 2; ++ry)
    #pragma unroll
    for (int p = 0; p < 4; ++p) acc[ry][p] = (f32x4){0.f, 0.f, 0.f, 0.f};

  const unsigned short* wbase = wimg + ((size_t)(wv * 16 + col)) * 40 + kg * 8;

  for (int ch = 0; ch < 18; ++ch) {
    const int tap = ch >> 1, cih = ch & 1;
    const int dy = tap / 3, dx = tap - dy * 3;
    const bf16x8s a = *(const bf16x8s*)(wbase + (size_t)ch * 64 * 40);
    const int cix = cih * 32 + kg * 8;
    #pragma unroll
    for (int ry = 0; ry < 2; ++ry)
      #pragma unroll
      for (int p = 0; p < 4; ++p) {
        const int c = p * 16 + col + dx;
        const bf16x8s b = *(const bf16x8s*)&in_s[((ry + dy) * 66 + c) * 72 + cix];
        acc[ry][p] = __builtin_amdgcn_mfma_f32_16x16x32_bf16(a, b, acc[ry][p], 0, 0, 0);
      }
  }

  const int cobase = wv * 16 + kg * 4;
  const float4 bb = *(const float4*)&bias[cobase];
  const float bv[4] = {bb.x, bb.y, bb.z, bb.w};
  #pragma unroll
  for (int ry = 0; ry < 2; ++ry)
    #pragma unroll
    for (int p = 0; p < 4; ++p) {
      const int x = x0 + p * 16 + col;
      #pragma unroll
      for (int r = 0; r < 4; ++r) {
        float t = acc[ry][p][r] + bv[r];
        t = t > 0.f ? t : 0.01f * t;
        out[(size_t)(n * 64 + cobase + r) * PS + (size_t)(y0 + ry) * RS + x] = t;
      }
    }
}

// ---------------- MFMA conv for Q, 2 rows/block: bf16 hi/lo out in rci layout ----------------
__global__ __launch_bounds__(256) void conv3mq(
    const unsigned short* __restrict__ inbf,
    const unsigned short* __restrict__ wimg,
    const float* __restrict__ bias,
    unsigned short* __restrict__ qhi, unsigned short* __restrict__ qlo) {
  const int x0 = blockIdx.x * 64;
  const int y0 = blockIdx.y * 2;
  const int n  = blockIdx.z;
  const int tid = threadIdx.x;
  const int lane = tid & 63;
  const int wv = tid >> 6;
  const int col = lane & 15;
  const int kg  = lane >> 4;

  __shared__ unsigned short in_s[4 * 66 * 72];

  {
    const unsigned short* src = inbf + ((size_t)n * 258 + y0) * 264 * 64;
    for (int pos = tid; pos < 264; pos += 256) {
      const int r = pos / 66, c = pos - r * 66;
      const unsigned short* s = src + ((size_t)r * 264 + x0 + c) * 64;
      unsigned short* d = &in_s[pos * 72];
      #pragma unroll
      for (int q = 0; q < 8; ++q)
        *(float4*)(d + q * 8) = *(const float4*)(s + q * 8);
    }
  }
  __syncthreads();

  f32x4 acc[2][4];
  #pragma unroll
  for (int ry = 0; ry < 2; ++ry)
    #pragma unroll
    for (int p = 0; p < 4; ++p) acc[ry][p] = (f32x4){0.f, 0.f, 0.f, 0.f};

  const unsigned short* wbase = wimg + ((size_t)(wv * 16 + col)) * 40 + kg * 8;

  for (int ch = 0; ch < 18; ++ch) {
    const int tap = ch >> 1, cih = ch & 1;
    const int dy = tap / 3, dx = tap - dy * 3;
    const bf16x8s a = *(const bf16x8s*)(wbase + (size_t)ch * 64 * 40);
    const int cix = cih * 32 + kg * 8;
    #pragma unroll
    for (int ry = 0; ry < 2; ++ry)
      #pragma unroll
      for (int p = 0; p < 4; ++p) {
        const int c = p * 16 + col + dx;
        const bf16x8s b = *(const bf16x8s*)&in_s[((ry + dy) * 66 + c) * 72 + cix];
        acc[ry][p] = __builtin_amdgcn_mfma_f32_16x16x32_bf16(a, b, acc[ry][p], 0, 0, 0);
      }
  }

  const int cobase = wv * 16 + kg * 4;
  const float4 bb = *(const float4*)&bias[cobase];
  const float bv[4] = {bb.x, bb.y, bb.z, bb.w};
  #pragma unroll
  for (int ry = 0; ry < 2; ++ry) {
    unsigned short* hb = qhi + ((size_t)n * 257 + (y0 + ry)) * 264 * 64;
    unsigned short* lb = qlo + ((size_t)n * 257 + (y0 + ry)) * 264 * 64;
    #pragma unroll
    for (int p = 0; p < 4; ++p) {
      const int x = x0 + p * 16 + col;
      unsigned long long hp = 0, lp = 0;
      #pragma unroll
      for (int r = 0; r < 4; ++r) {
        float t = acc[ry][p][r] + bv[r];
        t = t > 0.f ? t : 0.01f * t;
        const unsigned short h = f2bf(t);
        const unsigned short lo = f2bf(t - bf2f(h));
        hp |= ((unsigned long long)h) << (16 * r);
        lp |= ((unsigned long long)lo) << (16 * r);
      }
      *(unsigned long long*)(hb + (size_t)x * 64 + cobase) = hp;
      *(unsigned long long*)(lb + (size_t)x * 64 + cobase) = lp;
    }
  }
}

// ---------------- k-patch squared norms ----------------
__global__ void knorm_kernel(const float* __restrict__ kfea, float* __restrict__ norms) {
  const int l = blockIdx.x, n = blockIdx.y, c = threadIdx.x;
  const int ly = l >> 4, lx = l & 15;
  const float* base = kfea + ((size_t)(n * CI + c) * HK) * HK;
  float ss = 0.f;
  #pragma unroll
  for (int i = 0; i < KS; ++i) {
    const int r = 4 * ly + i;
    if (r >= HK) continue;
    #pragma unroll
    for (int j = 0; j < KS; ++j) {
      const int cc = 4 * lx + j;
      if (cc >= HK) continue;
      const float v = base[r * HK + cc];
      ss = fmaf(v, v, ss);
    }
  }
  for (int off = 32; off; off >>= 1) ss += __shfl_down(ss, off);
  if (c == 0) norms[n * LL + l] = ss;
}

__global__ void kscale_kernel(const float* __restrict__ norms, float* __restrict__ kscale) {
  const int n = blockIdx.x, t = threadIdx.x;
  float v = norms[n * LL + t];
  for (int off = 32; off; off >>= 1) v = fmaxf(v, __shfl_down(v, off));
  __shared__ float red[4];
  if ((t & 63) == 0) red[t >> 6] = v;
  __syncthreads();
  if (t == 0) {
    const float m = fmaxf(fmaxf(red[0], red[1]), fmaxf(red[2], red[3]));
    kscale[n] = 10.0f / sqrtf(m);
  }
}

// ---------------- K im2col hi/lo bf16: k[n][chunk 50][l 256][s 32] ----------------
__global__ void kp_gather2(const float* __restrict__ kfea, const float* __restrict__ kscale,
                           unsigned short* __restrict__ khi, unsigned short* __restrict__ klo) {
  const int tap = blockIdx.x, cih = blockIdx.y, n = blockIdx.z;
  const int s = threadIdx.x & 31, lg = threadIdx.x >> 5;
  const int i = tap / 5, j = tap % 5;
  const float sc = kscale[n];
  const float* kb = kfea + ((size_t)(n * 64 + cih * 32 + s) * 64) * 64;
  const size_t ob = (((size_t)n * 50 + tap * 2 + cih) * 256) * 32;
  for (int lb = 0; lb < 32; ++lb) {
    const int l = lb * 8 + lg;
    const int r = 4 * (l >> 4) + i, c = 4 * (l & 15) + j;
    float v = 0.f;
    if (r < 64 && c < 64) v = kb[r * 64 + c] * sc;
    const unsigned short h = f2bf(v);
    khi[ob + (size_t)l * 32 + s] = h;
    klo[ob + (size_t)l * 32 + s] = f2bf(v - bf2f(h));
  }
}

// ---------------- fused QK MFMA + softmax: K-split 8 waves, hi/lo 3-product ----------------
__global__ __launch_bounds__(512) void qk_fused(
    const unsigned short* __restrict__ qhi, const unsigned short* __restrict__ qlo,
    const unsigned short* __restrict__ khi, const unsigned short* __restrict__ klo,
    unsigned short* __restrict__ wnbf) {
  const int yb = blockIdx.x, n = blockIdx.y;
  const int tid = threadIdx.x;
  const int lane = tid & 63, wv = tid >> 6;
  const int kh = wv >> 2, lq = wv & 3;
  const int col = lane & 15, kg = lane >> 4;

  __shared__ float sc_s[64 * 260];   // 66.6 KB partial-score exchange
  __shared__ float red[64][5];
  __shared__ float redm[64];

  f32x4 acc[4][4];
  #pragma unroll
  for (int fm = 0; fm < 4; ++fm)
    #pragma unroll
    for (int fn = 0; fn < 4; ++fn) acc[fm][fn] = (f32x4){0.f, 0.f, 0.f, 0.f};

  const unsigned short* khb = khi + (size_t)n * 50 * 8192;
  const unsigned short* klb = klo + (size_t)n * 50 * 8192;
  const unsigned short* qhb = qhi + (size_t)n * QP2 * 64;
  const unsigned short* qlb = qlo + (size_t)n * QP2 * 64;

  const int ch0 = kh * 25;
  for (int cc = 0; cc < 25; ++cc) {
    const int ch = ch0 + cc;
    const int tap = ch >> 1, cih = ch & 1;
    const int i = tap / 5, j = tap - 5 * i;
    bf16x8s ah[4], al[4];
    #pragma unroll
    for (int fm = 0; fm < 4; ++fm) {
      const size_t qoff = (((size_t)(4 * yb + i) * 264) + 4 * (fm * 16 + col) + j) * 64
                        + cih * 32 + kg * 8;
      ah[fm] = *(const bf16x8s*)(qhb + qoff);
      al[fm] = *(const bf16x8s*)(qlb + qoff);
    }
    #pragma unroll
    for (int fn = 0; fn < 4; ++fn) {
      const size_t boff = ((size_t)ch * 256 + lq * 64 + fn * 16 + col) * 32 + kg * 8;
      const bf16x8s bh = *(const bf16x8s*)(khb + boff);
      const bf16x8s bl = *(const bf16x8s*)(klb + boff);
      #pragma unroll
      for (int fm = 0; fm < 4; ++fm) {
        acc[fm][fn] = __builtin_amdgcn_mfma_f32_16x16x32_bf16(ah[fm], bh, acc[fm][fn], 0, 0, 0);
        acc[fm][fn] = __builtin_amdgcn_mfma_f32_16x16x32_bf16(ah[fm], bl, acc[fm][fn], 0, 0, 0);
        acc[fm][fn] = __builtin_amdgcn_mfma_f32_16x16x32_bf16(al[fm], bh, acc[fm][fn], 0, 0, 0);
      }
    }
  }

  if (kh == 1) {
    #pragma unroll
    for (int fm = 0; fm < 4; ++fm)
      #pragma unroll
      for (int fn = 0; fn < 4; ++fn)
        #pragma unroll
        for (int r = 0; r < 4; ++r)
          sc_s[(fm * 16 + kg * 4 + r) * 260 + lq * 64 + fn * 16 + col] = acc[fm][fn][r];
  }
  __syncthreads();
  if (kh == 0) {
    #pragma unroll
    for (int fm = 0; fm < 4; ++fm)
      #pragma unroll
      for (int fn = 0; fn < 4; ++fn)
        #pragma unroll
        for (int r = 0; r < 4; ++r)
          acc[fm][fn][r] += sc_s[(fm * 16 + kg * 4 + r) * 260 + lq * 64 + fn * 16 + col];

    #pragma unroll
    for (int fm = 0; fm < 4; ++fm)
      #pragma unroll
      for (int r = 0; r < 4; ++r) {
        float m = fmaxf(fmaxf(acc[fm][0][r], acc[fm][1][r]),
                        fmaxf(acc[fm][2][r], acc[fm][3][r]));
        #pragma unroll
        for (int off = 1; off < 16; off <<= 1) m = fmaxf(m, __shfl_xor(m, off));
        if (col == 0) red[fm * 16 + kg * 4 + r][lq] = m;
      }
  }
  __syncthreads();
  if (tid < 64) {
    redm[tid] = fmaxf(fmaxf(red[tid][0], red[tid][1]),
                      fmaxf(red[tid][2], red[tid][3]));
  }
  __syncthreads();
  if (kh == 0) {
    #pragma unroll
    for (int fm = 0; fm < 4; ++fm)
      #pragma unroll
      for (int r = 0; r < 4; ++r) {
        const float bm = redm[fm * 16 + kg * 4 + r];
        float s = 0.f;
        #pragma unroll
        for (int fn = 0; fn < 4; ++fn) {
          const float e = __expf(acc[fm][fn][r] - bm);
          acc[fm][fn][r] = e;
          s += e;
        }
        #pragma unroll
        for (int off = 1; off < 16; off <<= 1) s += __shfl_xor(s, off);
        if (col == 0) red[fm * 16 + kg * 4 + r][lq] = s;
      }
  }
  __syncthreads();
  if (tid < 64) {
    redm[tid] = 1.0f / (red[tid][0] + red[tid][1] + red[tid][2] + red[tid][3]);
  }
  __syncthreads();
  if (kh == 0) {
    unsigned short* wb = wnbf + ((size_t)n * 4096 + (size_t)yb * 64) * 256;
    #pragma unroll
    for (int fm = 0; fm < 4; ++fm)
      #pragma unroll
      for (int r = 0; r < 4; ++r) {
        const int q = fm * 16 + kg * 4 + r;
        const float inv = redm[q];
        #pragma unroll
        for (int fn = 0; fn < 4; ++fn)
          wb[(size_t)q * 256 + lq * 64 + fn * 16 + col] = f2bf(acc[fm][fn][r] * inv);
      }
  }
}

// ---------------- v-patch transposed bf16 gather: vpt[n][bij][l] ----------------
__global__ void vpt_gather(const float* __restrict__ vfea, unsigned short* __restrict__ vpt) {
  const int l4 = threadIdx.x & 63, bj = threadIdx.x >> 6;
  const int bij = blockIdx.x * 4 + bj;
  const int n = blockIdx.y;
  const int ij = bij >> 6, b = bij & 63;
  unsigned short o[4] = {0, 0, 0, 0};
  if (ij < 25) {
    const int i = ij / 5, j = ij % 5;
    const int ly = l4 >> 2;
    const int r = 4 * ly + i;
    if (r < HK) {
      const float* base = vfea + ((size_t)(n * COC + b) * HK + r) * HK;
      #pragma unroll
      for (int e = 0; e < 4; ++e) {
        const int lx = (l4 & 3) * 4 + e;
        const int c = 4 * lx + j;
        if (c < HK) o[e] = f2bf(base[c]);
      }
    }
  }
  unsigned long long pack = (unsigned long long)o[0] | ((unsigned long long)o[1] << 16)
                          | ((unsigned long long)o[2] << 32) | ((unsigned long long)o[3] << 48);
  *(unsigned long long*)(vpt + ((size_t)n * NPAD + bij) * 256 + l4 * 4) = pack;
}

// ---------------- PV MFMA GEMM, LDS-free streaming: U (bf16) = wn x vpt^T ----------------
// grid (64 mt, 13 nt, NB), block 256 = 4 waves (2m x 2n); wave = 32m x 64n, acc[2][4].
// Both operands 16B-contiguous per lane; wn (2MB) + vpt (0.85MB) per batch are L2-resident.
__global__ __launch_bounds__(256) void pv_mfma(
    const unsigned short* __restrict__ wnb, const unsigned short* __restrict__ vpt,
    unsigned short* __restrict__ C0) {
  const int nz = blockIdx.z;
  const unsigned short* A = wnb + (size_t)nz * 4096 * 256;
  const unsigned short* B = vpt + (size_t)nz * NPAD * 256;
  unsigned short* C = C0 + (size_t)nz * 4096 * NPAD;
  const int m0 = blockIdx.x * 64;
  const int n0 = blockIdx.y * 128;
  const int tid = threadIdx.x;
  const int lane = tid & 63;
  const int wv = tid >> 6;
  const int wm = wv >> 1, wn_ = wv & 1;
  const int col = lane & 15, kg = lane >> 4;

  f32x4 acc[2][4];
  #pragma unroll
  for (int fm = 0; fm < 2; ++fm)
    #pragma unroll
    for (int fn = 0; fn < 4; ++fn) acc[fm][fn] = (f32x4){0.f, 0.f, 0.f, 0.f};

  const unsigned short* Abase = A + (size_t)(m0 + wm * 32 + col) * 256 + kg * 8;
  const unsigned short* Bbase = B + (size_t)(n0 + wn_ * 64 + col) * 256 + kg * 8;

  for (int k0 = 0; k0 < 256; k0 += 32) {
    bf16x8s a[2], b[4];
    #pragma unroll
    for (int fm = 0; fm < 2; ++fm)
      a[fm] = *(const bf16x8s*)(Abase + (size_t)(fm * 16) * 256 + k0);
    #pragma unroll
    for (int fn = 0; fn < 4; ++fn)
      b[fn] = *(const bf16x8s*)(Bbase + (size_t)(fn * 16) * 256 + k0);
    #pragma unroll
    for (int fm = 0; fm < 2; ++fm)
      #pragma unroll
      for (int fn = 0; fn < 4; ++fn)
        acc[fm][fn] = __builtin_amdgcn_mfma_f32_16x16x32_bf16(a[fm], b[fn], acc[fm][fn], 0, 0, 0);
  }

  #pragma unroll
  for (int fm = 0; fm < 2; ++fm) {
    #pragma unroll
    for (int fn = 0; fn < 4; ++fn) {
      const int cg = n0 + wn_ * 64 + fn * 16 + col;
      #pragma unroll
      for (int r = 0; r < 4; ++r) {
        const int rg = m0 + wm * 32 + fm * 16 + kg * 4 + r;
        C[(size_t)rg * NPAD + cg] = f2bf(acc[fm][fn][r]);
      }
    }
  }
}

// ---------------- conv-transpose gather (+ /6) -> resbf bf16 [258][264][64co] ----------------
__global__ __launch_bounds__(256) void u_scatter(
    const unsigned short* __restrict__ U0, unsigned short* __restrict__ resbf, int n0) {
  const int n = n0 + blockIdx.z;
  const unsigned short* U = U0 + (size_t)blockIdx.z * 4096 * NPAD;
  const int y = blockIdx.y;
  const int xt = blockIdx.x;
  const int tid = threadIdx.x;
  __shared__ float t_lds[64][65];
  const int ym = (y + 1) >> 2, yr = (y + 1) & 3;
  const bool v0 = (ym < 64);
  const bool v1 = (yr == 0 && ym >= 1);
  const int b = tid & 63, xg = tid >> 6;
  for (int xi = 0; xi < 16; ++xi) {
    const int x = xt * 64 + xg * 16 + xi;
    const int xm = (x + 1) >> 2, xr = (x + 1) & 3;
    const bool u0 = (xm < 64);
    const bool u1 = (xr == 0 && xm >= 1);
    float s = 0.f;
    if (v0) {
      const size_t rb = (size_t)(ym * 64) * NPAD;
      if (u0) s += bf2f(U[rb + (size_t)xm * NPAD + (yr * 5 + xr) * 64 + b]);
      if (u1) s += bf2f(U[rb + (size_t)(xm - 1) * NPAD + (yr * 5 + 4) * 64 + b]);
    }
    if (v1) {
      const size_t rb = (size_t)((ym - 1) * 64) * NPAD;
      if (u0) s += bf2f(U[rb + (size_t)xm * NPAD + (4 * 5 + xr) * 64 + b]);
      if (u1) s += bf2f(U[rb + (size_t)(xm - 1) * NPAD + (4 * 5 + 4) * 64 + b]);
    }
    t_lds[xg * 16 + xi][b] = s * (1.0f / 6.0f);
  }
  __syncthreads();
  unsigned short* db = resbf + (((size_t)n * 258 + (y + 1)) * 264) * 64;
  for (int xi = 0; xi < 16; ++xi) {
    const int x = xg * 16 + xi;
    db[(size_t)(xt * 64 + x + 1) * 64 + b] = f2bf(t_lds[x][b]);
  }
}

extern "C" void kernel_launch(void* const* d_in, const int* in_sizes, int n_in,
                              void* d_out, int out_size, void* d_ws, size_t ws_size,
                              hipStream_t stream) {
  const float* ms   = (const float*)d_in[0];
  const float* pan  = (const float*)d_in[1];
  const float* pan2 = (const float*)d_in[2];
  const float* Wq   = (const float*)d_in[3];
  const float* bq   = (const float*)d_in[4];
  const float* Wk   = (const float*)d_in[5];
  const float* bk   = (const float*)d_in[6];
  const float* Wv   = (const float*)d_in[7];
  const float* bv   = (const float*)d_in[8];
  const float* Wr   = (const float*)d_in[9];
  const float* br   = (const float*)d_in[10];
  float* out = (float*)d_out;

  float* ws = (float*)d_ws;
  const size_t SZ_QP  = (size_t)NB * CI * QP2;               // qhi|qlo bf16 (34.74M floats)
  const size_t SZ_K   = (size_t)NB * CI * HK * HK;           // 2.10M
  const size_t SZ_WN  = (size_t)NB * 64 * 64 * LL;           // wn bf16 = SZ_WN/2 floats
  const size_t SZ_VPT = (size_t)NB * NPAD * 256 / 2;         // 1.70M floats (bf16)
  const size_t SZ_KP  = (size_t)NB * 50 * 256 * 32;          // khi|klo bf16 (3.28M floats)
  const size_t SZ_PS  = (size_t)NB * CI * 66 * 72;           // 2.43M (rci bf16 small: 1.22M used)
  const size_t SZ_WI4 = 4 * 23040;                           // 4 weight images
  const size_t SZ_U1F = (size_t)4096 * NPAD / 2;             // U bf16, floats per batch (3.41M)
  const size_t SZ_UAF = (size_t)NB * SZ_U1F;                 // 27.26M floats

  float* q_pad   = ws;                    // qhi|qlo bf16; later resbf
  float* k_fea   = q_pad + SZ_QP;
  float* v_fea   = k_fea + SZ_K;
  float* wnbf_f  = v_fea + SZ_K;
  float* vptbf_f = wnbf_f + SZ_WN / 2;
  float* kp      = vptbf_f + SZ_VPT;      // khi|klo bf16
  float* norms   = kp + SZ_KP;
  float* kscale  = norms + NB * LL;
  float* wimgf   = kscale + 64;           // 4 images: k,v,q,r
  float* msrci_f = wimgf + SZ_WI4;
  float* p2rci_f = msrci_f + SZ_PS;
  float* tail    = p2rci_f + SZ_PS;       // panbf -> U (bf16)

  unsigned short* qhi  = (unsigned short*)q_pad;
  unsigned short* qlo  = qhi + (size_t)NB * QP2 * 64;
  unsigned short* khi  = (unsigned short*)kp;
  unsigned short* klo  = khi + (size_t)NB * 50 * 256 * 32;
  unsigned short* wimg  = (unsigned short*)wimgf;
  unsigned short* wimgk = wimg;
  unsigned short* wimgv = wimg + (size_t)1 * 18 * 64 * 40;
  unsigned short* wimgq = wimg + (size_t)2 * 18 * 64 * 40;
  unsigned short* wimgr = wimg + (size_t)3 * 18 * 64 * 40;
  unsigned short* msrci = (unsigned short*)msrci_f;
  unsigned short* p2rci = (unsigned short*)p2rci_f;
  unsigned short* wnbf  = (unsigned short*)wnbf_f;
  unsigned short* vptbf = (unsigned short*)vptbf_f;
  unsigned short* panbf = (unsigned short*)tail;
  unsigned short* U     = (unsigned short*)tail;
  unsigned short* resbf = (unsigned short*)q_pad;   // q dead after qk_fused

  const size_t base_elems = (size_t)(tail - ws);
  const bool batched = ws_size >= (base_elems + SZ_UAF) * sizeof(float);

  // weight prep (k,v,q,r in one launch)
  wtrans_mfma4<<<dim3(18, 4), 256, 0, stream>>>(Wk, Wv, Wq, Wr, wimg);

  // pad inputs to rci bf16 (ms+pan2 in one launch; pan big)
  pad_rci_s2<<<dim3(66, NB, 2), 256, 0, stream>>>(ms, msrci, pan2, p2rci);
  pad_rci<<<dim3(4, 258, NB), 256, 0, stream>>>(pan, panbf);

  // feature convs: ALL MFMA bf16. k/v small (planar fp32 out); q big (hi/lo rci out)
  conv3m<<<dim3(1, 32, NB), 256, 0, stream>>>(p2rci, wimgk, bk, k_fea, HK * HK, HK,
                                              72 * 64, (long long)66 * 72 * 64);
  conv3m<<<dim3(1, 32, NB), 256, 0, stream>>>(msrci, wimgv, bv, v_fea, HK * HK, HK,
                                              72 * 64, (long long)66 * 72 * 64);
  conv3mq<<<dim3(4, 128, NB), 256, 0, stream>>>(panbf, wimgq, bq, qhi, qlo);
  qz<<<dim3(NB), 256, 0, stream>>>(qhi, qlo);

  // k-patch max norm -> scale
  knorm_kernel<<<dim3(LL, NB), 64, 0, stream>>>(k_fea, norms);
  kscale_kernel<<<NB, 256, 0, stream>>>(norms, kscale);

  // K im2col hi/lo (kscale folded)
  kp_gather2<<<dim3(25, 2, NB), 256, 0, stream>>>(k_fea, kscale, khi, klo);

  // fused QK MFMA (K-split, 64q blocks) + softmax -> bf16 wn  [panbf dead afterwards]
  qk_fused<<<dim3(64, NB), 512, 0, stream>>>(qhi, qlo, khi, klo, wnbf);

  // resbf borders (aliases q hi/lo; dead after qk_fused)
  rbz<<<dim3(NB), 256, 0, stream>>>(resbf);

  // v patch bf16 transposed matrix
  vpt_gather<<<dim3(NPAD / 4, NB), 256, 0, stream>>>(v_fea, vptbf);

  // PV MFMA streaming (bf16 U) + conv-transpose gather
  if (batched) {
    pv_mfma<<<dim3(64, 13, NB), 256, 0, stream>>>(wnbf, vptbf, U);
    u_scatter<<<dim3(4, HQ, NB), 256, 0, stream>>>(U, resbf, 0);
  } else {
    for (int n = 0; n < NB; ++n) {
      pv_mfma<<<dim3(64, 13, 1), 256, 0, stream>>>(wnbf + (size_t)n * 4096 * 256,
                                                   vptbf + (size_t)n * NPAD * 256, U);
      u_scatter<<<dim3(4, HQ, 1), 256, 0, stream>>>(U, resbf, n);
    }
  }

  // final conv (MFMA bf16, 2 rows/block) -> d_out fp32
  conv3m<<<dim3(4, 128, NB), 256, 0, stream>>>(resbf, wimgr, br, out, HQ * HQ, HQ,
                                               264 * 64, (long long)258 * 264 * 64);
}

// Round 21
// 633.420 us; speedup vs baseline: 1.1106x; 1.1106x over previous
//
#include <hip/hip_runtime.h>
#include <math.h>

#define NB   8
#define CI   64
#define COC  64
#define HQ   256
#define HK   64
#define KS   5
#define LL   256
#define NPAD 1664
#define QP2  (257 * 264)   // q bf16 plane (rows 0..256, row 256 = same-pad zeros)

typedef __attribute__((ext_vector_type(8))) short bf16x8s;
typedef __attribute__((ext_vector_type(4))) float f32x4;

static __device__ __forceinline__ unsigned short f2bf(float f) {
  union { float f; unsigned u; } v; v.f = f;
  unsigned r = v.u + 0x7FFF + ((v.u >> 16) & 1);
  return (unsigned short)(r >> 16);
}
static __device__ __forceinline__ float bf2f(unsigned short h) {
  union { unsigned u; float f; } v; v.u = ((unsigned)h) << 16; return v.f;
}

// ---------------- weight images for conv3m: 4 weights in one launch ----------------
__global__ void wtrans_mfma4(const float* __restrict__ W0, const float* __restrict__ W1,
                             const float* __restrict__ W2, const float* __restrict__ W3,
                             unsigned short* __restrict__ wimg) {
  const int ch = blockIdx.x, wsel = blockIdx.y;
  const float* Wt = (wsel == 0) ? W0 : (wsel == 1) ? W1 : (wsel == 2) ? W2 : W3;
  const int tap = ch >> 1, cih = ch & 1;
  unsigned short* dst = wimg + (size_t)wsel * 18 * 64 * 40 + (size_t)ch * 64 * 40;
  for (int idx = threadIdx.x; idx < 64 * 40; idx += 256) {
    const int co = idx / 40, s = idx - co * 40;
    unsigned short v = 0;
    if (s < 32) v = f2bf(Wt[((size_t)co * 64 + cih * 32 + s) * 9 + tap]);
    dst[idx] = v;
  }
}

// ---------------- pan fp32 [ci][256][256] -> bf16 [row 258][col 264][ci 64] ----------------
__global__ void pad_rci(const float* __restrict__ src, unsigned short* __restrict__ dst) {
  const int ct = blockIdx.x, g = blockIdx.y, n = blockIdx.z;
  const int c0 = ct * 66;
  __shared__ float t[64 * 68];
  const int jl = threadIdx.x & 63, cg = threadIdx.x >> 6;
  const int row = g - 1;
  const bool rok = (row >= 0 && row < 256);
  for (int ci = cg; ci < 64; ci += 4) {
    #pragma unroll
    for (int jb = 0; jb < 2; ++jb) {
      const int j = jl + jb * 64;
      if (j < 66) {
        const int x = c0 - 1 + j;
        float v = 0.f;
        if (rok && x >= 0 && x < 256)
          v = src[(((size_t)n * 64 + ci) * 256 + row) * 256 + x];
        t[ci * 68 + j] = v;
      }
    }
  }
  __syncthreads();
  const int cil = threadIdx.x & 63, cc = threadIdx.x >> 6;
  unsigned short* db = dst + (((size_t)n * 258 + g) * 264) * 64;
  for (int c = cc; c < 66; c += 4)
    db[(size_t)(c0 + c) * 64 + cil] = f2bf(t[cil * 68 + c]);
}

// ---------------- small fp32 [ci][64][64] -> bf16 [row 66][col 72][ci 64], 2 srcs ----------------
__global__ void pad_rci_s2(const float* __restrict__ s0, unsigned short* __restrict__ d0,
                           const float* __restrict__ s1, unsigned short* __restrict__ d1) {
  const int g = blockIdx.x;
  const int n = blockIdx.y;
  const int sel = blockIdx.z;
  const float* src = sel ? s1 : s0;
  unsigned short* dst = sel ? d1 : d0;
  __shared__ float t[64 * 68];
  const int jl = threadIdx.x & 63, cg = threadIdx.x >> 6;
  const int row = g - 1;
  const bool rok = (row >= 0 && row < 64);
  for (int ci = cg; ci < 64; ci += 4) {
    #pragma unroll
    for (int jb = 0; jb < 2; ++jb) {
      const int j = jl + jb * 64;
      if (j < 66) {
        const int x = j - 1;
        float v = 0.f;
        if (rok && x >= 0 && x < 64)
          v = src[(((size_t)n * 64 + ci) * 64 + row) * 64 + x];
        t[ci * 68 + j] = v;
      }
    }
  }
  __syncthreads();
  const int cil = threadIdx.x & 63, cc = threadIdx.x >> 6;
  unsigned short* db = dst + ((size_t)n * 66 + g) * 72 * 64;
  for (int c = cc; c < 66; c += 4)
    db[(size_t)c * 64 + cil] = f2bf(t[cil * 68 + c]);
}

// zero borders of resbf ([258][264][64])
__global__ void rbz(unsigned short* __restrict__ resbf) {
  const int n = blockIdx.x;
  unsigned short* b = resbf + (size_t)n * 258 * 264 * 64;
  for (int idx = threadIdx.x; idx < 264 * 64; idx += 256) {
    b[idx] = 0;
    b[(size_t)257 * 264 * 64 + idx] = 0;
  }
  for (int idx = threadIdx.x; idx < 256 * 64; idx += 256) {
    const int r = idx >> 6, ci = idx & 63;
    b[((size_t)(r + 1) * 264) * 64 + ci] = 0;
    b[((size_t)(r + 1) * 264 + 257) * 64 + ci] = 0;
  }
}

// zero same-pad strips of q hi/lo ([257][264][64]): row 256 full, col 256 rows 0..255
__global__ void qz(unsigned short* __restrict__ qhi, unsigned short* __restrict__ qlo) {
  const int n = blockIdx.x;
  unsigned short* bh = qhi + (size_t)n * QP2 * 64;
  unsigned short* bl = qlo + (size_t)n * QP2 * 64;
  for (int g = threadIdx.x; g < 4224; g += 256) {
    ((unsigned long long*)(bh + (size_t)256 * 264 * 64))[g] = 0ull;
    ((unsigned long long*)(bl + (size_t)256 * 264 * 64))[g] = 0ull;
  }
  for (int g = threadIdx.x; g < 4096; g += 256) {
    const int r = g >> 4, q = g & 15;
    const size_t off = ((size_t)r * 264 + 256) * 64 + q * 4;
    *(unsigned long long*)(bh + off) = 0ull;
    *(unsigned long long*)(bl + off) = 0ull;
  }
}

// ---------------- MFMA conv 3x3 + bias + leaky relu, 2 rows/block (bf16 in, fp32 out) ----------------
__global__ __launch_bounds__(256) void conv3m(
    const unsigned short* __restrict__ inbf,
    const unsigned short* __restrict__ wimg,
    const float* __restrict__ bias,
    float* __restrict__ out, int PS, int RS, int inRS, long long inIS) {
  const int x0 = blockIdx.x * 64;
  const int y0 = blockIdx.y * 2;
  const int n  = blockIdx.z;
  const int tid = threadIdx.x;
  const int lane = tid & 63;
  const int wv = tid >> 6;
  const int col = lane & 15;
  const int kg  = lane >> 4;

  __shared__ unsigned short in_s[4 * 66 * 72];

  {
    const unsigned short* src = inbf + (size_t)n * inIS + (size_t)y0 * inRS;
    for (int pos = tid; pos < 264; pos += 256) {
      const int r = pos / 66, c = pos - r * 66;
      const unsigned short* s = src + (size_t)r * inRS + (size_t)(x0 + c) * 64;
      unsigned short* d = &in_s[pos * 72];
      #pragma unroll
      for (int q = 0; q < 8; ++q)
        *(float4*)(d + q * 8) = *(const float4*)(s + q * 8);
    }
  }
  __syncthreads();

  f32x4 acc[2][4];
  #pragma unroll
  for (int ry = 0; ry < 2; ++ry)
    #pragma unroll
    for (int p = 0; p < 4; ++p) acc[ry][p] = (f32x4){0.f, 0.f, 0.f, 0.f};

  const unsigned short* wbase = wimg + ((size_t)(wv * 16 + col)) * 40 + kg * 8;

  for (int ch = 0; ch < 18; ++ch) {
    const int tap = ch >> 1, cih = ch & 1;
    const int dy = tap / 3, dx = tap - dy * 3;
    const bf16x8s a = *(const bf16x8s*)(wbase + (size_t)ch * 64 * 40);
    const int cix = cih * 32 + kg * 8;
    #pragma unroll
    for (int ry = 0; ry < 2; ++ry)
      #pragma unroll
      for (int p = 0; p < 4; ++p) {
        const int c = p * 16 + col + dx;
        const bf16x8s b = *(const bf16x8s*)&in_s[((ry + dy) * 66 + c) * 72 + cix];
        acc[ry][p] = __builtin_amdgcn_mfma_f32_16x16x32_bf16(a, b, acc[ry][p], 0, 0, 0);
      }
  }

  const int cobase = wv * 16 + kg * 4;
  const float4 bb = *(const float4*)&bias[cobase];
  const float bv[4] = {bb.x, bb.y, bb.z, bb.w};
  #pragma unroll
  for (int ry = 0; ry < 2; ++ry)
    #pragma unroll
    for (int p = 0; p < 4; ++p) {
      const int x = x0 + p * 16 + col;
      #pragma unroll
      for (int r = 0; r < 4; ++r) {
        float t = acc[ry][p][r] + bv[r];
        t = t > 0.f ? t : 0.01f * t;
        out[(size_t)(n * 64 + cobase + r) * PS + (size_t)(y0 + ry) * RS + x] = t;
      }
    }
}

// ---------------- MFMA conv for Q, 2 rows/block: bf16 hi/lo out in rci layout ----------------
__global__ __launch_bounds__(256) void conv3mq(
    const unsigned short* __restrict__ inbf,
    const unsigned short* __restrict__ wimg,
    const float* __restrict__ bias,
    unsigned short* __restrict__ qhi, unsigned short* __restrict__ qlo) {
  const int x0 = blockIdx.x * 64;
  const int y0 = blockIdx.y * 2;
  const int n  = blockIdx.z;
  const int tid = threadIdx.x;
  const int lane = tid & 63;
  const int wv = tid >> 6;
  const int col = lane & 15;
  const int kg  = lane >> 4;

  __shared__ unsigned short in_s[4 * 66 * 72];

  {
    const unsigned short* src = inbf + ((size_t)n * 258 + y0) * 264 * 64;
    for (int pos = tid; pos < 264; pos += 256) {
      const int r = pos / 66, c = pos - r * 66;
      const unsigned short* s = src + ((size_t)r * 264 + x0 + c) * 64;
      unsigned short* d = &in_s[pos * 72];
      #pragma unroll
      for (int q = 0; q < 8; ++q)
        *(float4*)(d + q * 8) = *(const float4*)(s + q * 8);
    }
  }
  __syncthreads();

  f32x4 acc[2][4];
  #pragma unroll
  for (int ry = 0; ry < 2; ++ry)
    #pragma unroll
    for (int p = 0; p < 4; ++p) acc[ry][p] = (f32x4){0.f, 0.f, 0.f, 0.f};

  const unsigned short* wbase = wimg + ((size_t)(wv * 16 + col)) * 40 + kg * 8;

  for (int ch = 0; ch < 18; ++ch) {
    const int tap = ch >> 1, cih = ch & 1;
    const int dy = tap / 3, dx = tap - dy * 3;
    const bf16x8s a = *(const bf16x8s*)(wbase + (size_t)ch * 64 * 40);
    const int cix = cih * 32 + kg * 8;
    #pragma unroll
    for (int ry = 0; ry < 2; ++ry)
      #pragma unroll
      for (int p = 0; p < 4; ++p) {
        const int c = p * 16 + col + dx;
        const bf16x8s b = *(const bf16x8s*)&in_s[((ry + dy) * 66 + c) * 72 + cix];
        acc[ry][p] = __builtin_amdgcn_mfma_f32_16x16x32_bf16(a, b, acc[ry][p], 0, 0, 0);
      }
  }

  const int cobase = wv * 16 + kg * 4;
  const float4 bb = *(const float4*)&bias[cobase];
  const float bv[4] = {bb.x, bb.y, bb.z, bb.w};
  #pragma unroll
  for (int ry = 0; ry < 2; ++ry) {
    unsigned short* hb = qhi + ((size_t)n * 257 + (y0 + ry)) * 264 * 64;
    unsigned short* lb = qlo + ((size_t)n * 257 + (y0 + ry)) * 264 * 64;
    #pragma unroll
    for (int p = 0; p < 4; ++p) {
      const int x = x0 + p * 16 + col;
      unsigned long long hp = 0, lp = 0;
      #pragma unroll
      for (int r = 0; r < 4; ++r) {
        float t = acc[ry][p][r] + bv[r];
        t = t > 0.f ? t : 0.01f * t;
        const unsigned short h = f2bf(t);
        const unsigned short lo = f2bf(t - bf2f(h));
        hp |= ((unsigned long long)h) << (16 * r);
        lp |= ((unsigned long long)lo) << (16 * r);
      }
      *(unsigned long long*)(hb + (size_t)x * 64 + cobase) = hp;
      *(unsigned long long*)(lb + (size_t)x * 64 + cobase) = lp;
    }
  }
}

// ---------------- k-patch squared norms ----------------
__global__ void knorm_kernel(const float* __restrict__ kfea, float* __restrict__ norms) {
  const int l = blockIdx.x, n = blockIdx.y, c = threadIdx.x;
  const int ly = l >> 4, lx = l & 15;
  const float* base = kfea + ((size_t)(n * CI + c) * HK) * HK;
  float ss = 0.f;
  #pragma unroll
  for (int i = 0; i < KS; ++i) {
    const int r = 4 * ly + i;
    if (r >= HK) continue;
    #pragma unroll
    for (int j = 0; j < KS; ++j) {
      const int cc = 4 * lx + j;
      if (cc >= HK) continue;
      const float v = base[r * HK + cc];
      ss = fmaf(v, v, ss);
    }
  }
  for (int off = 32; off; off >>= 1) ss += __shfl_down(ss, off);
  if (c == 0) norms[n * LL + l] = ss;
}

__global__ void kscale_kernel(const float* __restrict__ norms, float* __restrict__ kscale) {
  const int n = blockIdx.x, t = threadIdx.x;
  float v = norms[n * LL + t];
  for (int off = 32; off; off >>= 1) v = fmaxf(v, __shfl_down(v, off));
  __shared__ float red[4];
  if ((t & 63) == 0) red[t >> 6] = v;
  __syncthreads();
  if (t == 0) {
    const float m = fmaxf(fmaxf(red[0], red[1]), fmaxf(red[2], red[3]));
    kscale[n] = 10.0f / sqrtf(m);
  }
}

// ---------------- K im2col hi/lo bf16: k[n][chunk 50][l 256][s 32] ----------------
__global__ void kp_gather2(const float* __restrict__ kfea, const float* __restrict__ kscale,
                           unsigned short* __restrict__ khi, unsigned short* __restrict__ klo) {
  const int tap = blockIdx.x, cih = blockIdx.y, n = blockIdx.z;
  const int s = threadIdx.x & 31, lg = threadIdx.x >> 5;
  const int i = tap / 5, j = tap % 5;
  const float sc = kscale[n];
  const float* kb = kfea + ((size_t)(n * 64 + cih * 32 + s) * 64) * 64;
  const size_t ob = (((size_t)n * 50 + tap * 2 + cih) * 256) * 32;
  for (int lb = 0; lb < 32; ++lb) {
    const int l = lb * 8 + lg;
    const int r = 4 * (l >> 4) + i, c = 4 * (l & 15) + j;
    float v = 0.f;
    if (r < 64 && c < 64) v = kb[r * 64 + c] * sc;
    const unsigned short h = f2bf(v);
    khi[ob + (size_t)l * 32 + s] = h;
    klo[ob + (size_t)l * 32 + s] = f2bf(v - bf2f(h));
  }
}

// ---------------- fused QK MFMA + softmax: K-split 8 waves, hi/lo 3-product ----------------
__global__ __launch_bounds__(512) void qk_fused(
    const unsigned short* __restrict__ qhi, const unsigned short* __restrict__ qlo,
    const unsigned short* __restrict__ khi, const unsigned short* __restrict__ klo,
    unsigned short* __restrict__ wnbf) {
  const int yb = blockIdx.x, n = blockIdx.y;
  const int tid = threadIdx.x;
  const int lane = tid & 63, wv = tid >> 6;
  const int kh = wv >> 2, lq = wv & 3;
  const int col = lane & 15, kg = lane >> 4;

  __shared__ float sc_s[64 * 260];   // 66.6 KB partial-score exchange
  __shared__ float red[64][5];
  __shared__ float redm[64];

  f32x4 acc[4][4];
  #pragma unroll
  for (int fm = 0; fm < 4; ++fm)
    #pragma unroll
    for (int fn = 0; fn < 4; ++fn) acc[fm][fn] = (f32x4){0.f, 0.f, 0.f, 0.f};

  const unsigned short* khb = khi + (size_t)n * 50 * 8192;
  const unsigned short* klb = klo + (size_t)n * 50 * 8192;
  const unsigned short* qhb = qhi + (size_t)n * QP2 * 64;
  const unsigned short* qlb = qlo + (size_t)n * QP2 * 64;

  const int ch0 = kh * 25;
  for (int cc = 0; cc < 25; ++cc) {
    const int ch = ch0 + cc;
    const int tap = ch >> 1, cih = ch & 1;
    const int i = tap / 5, j = tap - 5 * i;
    bf16x8s ah[4], al[4];
    #pragma unroll
    for (int fm = 0; fm < 4; ++fm) {
      const size_t qoff = (((size_t)(4 * yb + i) * 264) + 4 * (fm * 16 + col) + j) * 64
                        + cih * 32 + kg * 8;
      ah[fm] = *(const bf16x8s*)(qhb + qoff);
      al[fm] = *(const bf16x8s*)(qlb + qoff);
    }
    #pragma unroll
    for (int fn = 0; fn < 4; ++fn) {
      const size_t boff = ((size_t)ch * 256 + lq * 64 + fn * 16 + col) * 32 + kg * 8;
      const bf16x8s bh = *(const bf16x8s*)(khb + boff);
      const bf16x8s bl = *(const bf16x8s*)(klb + boff);
      #pragma unroll
      for (int fm = 0; fm < 4; ++fm) {
        acc[fm][fn] = __builtin_amdgcn_mfma_f32_16x16x32_bf16(ah[fm], bh, acc[fm][fn], 0, 0, 0);
        acc[fm][fn] = __builtin_amdgcn_mfma_f32_16x16x32_bf16(ah[fm], bl, acc[fm][fn], 0, 0, 0);
        acc[fm][fn] = __builtin_amdgcn_mfma_f32_16x16x32_bf16(al[fm], bh, acc[fm][fn], 0, 0, 0);
      }
    }
  }

  if (kh == 1) {
    #pragma unroll
    for (int fm = 0; fm < 4; ++fm)
      #pragma unroll
      for (int fn = 0; fn < 4; ++fn)
        #pragma unroll
        for (int r = 0; r < 4; ++r)
          sc_s[(fm * 16 + kg * 4 + r) * 260 + lq * 64 + fn * 16 + col] = acc[fm][fn][r];
  }
  __syncthreads();
  if (kh == 0) {
    #pragma unroll
    for (int fm = 0; fm < 4; ++fm)
      #pragma unroll
      for (int fn = 0; fn < 4; ++fn)
        #pragma unroll
        for (int r = 0; r < 4; ++r)
          acc[fm][fn][r] += sc_s[(fm * 16 + kg * 4 + r) * 260 + lq * 64 + fn * 16 + col];

    #pragma unroll
    for (int fm = 0; fm < 4; ++fm)
      #pragma unroll
      for (int r = 0; r < 4; ++r) {
        float m = fmaxf(fmaxf(acc[fm][0][r], acc[fm][1][r]),
                        fmaxf(acc[fm][2][r], acc[fm][3][r]));
        #pragma unroll
        for (int off = 1; off < 16; off <<= 1) m = fmaxf(m, __shfl_xor(m, off));
        if (col == 0) red[fm * 16 + kg * 4 + r][lq] = m;
      }
  }
  __syncthreads();
  if (tid < 64) {
    redm[tid] = fmaxf(fmaxf(red[tid][0], red[tid][1]),
                      fmaxf(red[tid][2], red[tid][3]));
  }
  __syncthreads();
  if (kh == 0) {
    #pragma unroll
    for (int fm = 0; fm < 4; ++fm)
      #pragma unroll
      for (int r = 0; r < 4; ++r) {
        const float bm = redm[fm * 16 + kg * 4 + r];
        float s = 0.f;
        #pragma unroll
        for (int fn = 0; fn < 4; ++fn) {
          const float e = __expf(acc[fm][fn][r] - bm);
          acc[fm][fn][r] = e;
          s += e;
        }
        #pragma unroll
        for (int off = 1; off < 16; off <<= 1) s += __shfl_xor(s, off);
        if (col == 0) red[fm * 16 + kg * 4 + r][lq] = s;
      }
  }
  __syncthreads();
  if (tid < 64) {
    redm[tid] = 1.0f / (red[tid][0] + red[tid][1] + red[tid][2] + red[tid][3]);
  }
  __syncthreads();
  if (kh == 0) {
    unsigned short* wb = wnbf + ((size_t)n * 4096 + (size_t)yb * 64) * 256;
    #pragma unroll
    for (int fm = 0; fm < 4; ++fm)
      #pragma unroll
      for (int r = 0; r < 4; ++r) {
        const int q = fm * 16 + kg * 4 + r;
        const float inv = redm[q];
        #pragma unroll
        for (int fn = 0; fn < 4; ++fn)
          wb[(size_t)q * 256 + lq * 64 + fn * 16 + col] = f2bf(acc[fm][fn][r] * inv);
      }
  }
}

// ---------------- v-patch transposed bf16 gather: vpt[n][bij][l] ----------------
__global__ void vpt_gather(const float* __restrict__ vfea, unsigned short* __restrict__ vpt) {
  const int l4 = threadIdx.x & 63, bj = threadIdx.x >> 6;
  const int bij = blockIdx.x * 4 + bj;
  const int n = blockIdx.y;
  const int ij = bij >> 6, b = bij & 63;
  unsigned short o[4] = {0, 0, 0, 0};
  if (ij < 25) {
    const int i = ij / 5, j = ij % 5;
    const int ly = l4 >> 2;
    const int r = 4 * ly + i;
    if (r < HK) {
      const float* base = vfea + ((size_t)(n * COC + b) * HK + r) * HK;
      #pragma unroll
      for (int e = 0; e < 4; ++e) {
        const int lx = (l4 & 3) * 4 + e;
        const int c = 4 * lx + j;
        if (c < HK) o[e] = f2bf(base[c]);
      }
    }
  }
  unsigned long long pack = (unsigned long long)o[0] | ((unsigned long long)o[1] << 16)
                          | ((unsigned long long)o[2] << 32) | ((unsigned long long)o[3] << 48);
  *(unsigned long long*)(vpt + ((size_t)n * NPAD + bij) * 256 + l4 * 4) = pack;
}

// ---------------- PV MFMA GEMM (LDS double-staged): U (bf16) = wn x vpt^T ----------------
__global__ __launch_bounds__(256) void pv_mfma(
    const unsigned short* __restrict__ wnb, const unsigned short* __restrict__ vpt,
    unsigned short* __restrict__ C0) {
  const int nz = blockIdx.z;
  const unsigned short* A = wnb + (size_t)nz * 4096 * 256;
  const unsigned short* B = vpt + (size_t)nz * NPAD * 256;
  unsigned short* C = C0 + (size_t)nz * 4096 * NPAD;
  const int m0 = blockIdx.x * 64;
  const int n0 = blockIdx.y * 128;
  const int tid = threadIdx.x;
  const int lane = tid & 63;
  const int wv = tid >> 6;
  const int wm = wv >> 1, wn_ = wv & 1;
  const int col = lane & 15, kg = lane >> 4;

  __shared__ unsigned short A_s[64 * 40];
  __shared__ unsigned short B_s[128 * 40];

  f32x4 acc[2][4];
  #pragma unroll
  for (int fm = 0; fm < 2; ++fm)
    #pragma unroll
    for (int fn = 0; fn < 4; ++fn) acc[fm][fn] = (f32x4){0.f, 0.f, 0.f, 0.f};

  for (int k0 = 0; k0 < 256; k0 += 32) {
    __syncthreads();
    {
      const int row = tid >> 2, q = tid & 3;
      *(float4*)&A_s[row * 40 + q * 8] =
          *(const float4*)&A[(size_t)(m0 + row) * 256 + k0 + q * 8];
    }
    {
      const int row = tid >> 1, hh = tid & 1;
      *(float4*)&B_s[row * 40 + hh * 16] =
          *(const float4*)&B[(size_t)(n0 + row) * 256 + k0 + hh * 16];
      *(float4*)&B_s[row * 40 + hh * 16 + 8] =
          *(const float4*)&B[(size_t)(n0 + row) * 256 + k0 + hh * 16 + 8];
    }
    __syncthreads();

    bf16x8s a[2], b[4];
    #pragma unroll
    for (int fm = 0; fm < 2; ++fm)
      a[fm] = *(const bf16x8s*)&A_s[(wm * 32 + fm * 16 + col) * 40 + kg * 8];
    #pragma unroll
    for (int fn = 0; fn < 4; ++fn)
      b[fn] = *(const bf16x8s*)&B_s[(wn_ * 64 + fn * 16 + col) * 40 + kg * 8];
    #pragma unroll
    for (int fm = 0; fm < 2; ++fm)
      #pragma unroll
      for (int fn = 0; fn < 4; ++fn)
        acc[fm][fn] = __builtin_amdgcn_mfma_f32_16x16x32_bf16(a[fm], b[fn], acc[fm][fn], 0, 0, 0);
  }

  #pragma unroll
  for (int fm = 0; fm < 2; ++fm) {
    #pragma unroll
    for (int fn = 0; fn < 4; ++fn) {
      const int cg = n0 + wn_ * 64 + fn * 16 + col;
      #pragma unroll
      for (int r = 0; r < 4; ++r) {
        const int rg = m0 + wm * 32 + fm * 16 + kg * 4 + r;
        C[(size_t)rg * NPAD + cg] = f2bf(acc[fm][fn][r]);
      }
    }
  }
}

// ---------------- conv-transpose gather (+ /6) -> resbf bf16 [258][264][64co] ----------------
__global__ __launch_bounds__(256) void u_scatter(
    const unsigned short* __restrict__ U0, unsigned short* __restrict__ resbf, int n0) {
  const int n = n0 + blockIdx.z;
  const unsigned short* U = U0 + (size_t)blockIdx.z * 4096 * NPAD;
  const int y = blockIdx.y;
  const int xt = blockIdx.x;
  const int tid = threadIdx.x;
  __shared__ float t_lds[64][65];
  const int ym = (y + 1) >> 2, yr = (y + 1) & 3;
  const bool v0 = (ym < 64);
  const bool v1 = (yr == 0 && ym >= 1);
  const int b = tid & 63, xg = tid >> 6;
  for (int xi = 0; xi < 16; ++xi) {
    const int x = xt * 64 + xg * 16 + xi;
    const int xm = (x + 1) >> 2, xr = (x + 1) & 3;
    const bool u0 = (xm < 64);
    const bool u1 = (xr == 0 && xm >= 1);
    float s = 0.f;
    if (v0) {
      const size_t rb = (size_t)(ym * 64) * NPAD;
      if (u0) s += bf2f(U[rb + (size_t)xm * NPAD + (yr * 5 + xr) * 64 + b]);
      if (u1) s += bf2f(U[rb + (size_t)(xm - 1) * NPAD + (yr * 5 + 4) * 64 + b]);
    }
    if (v1) {
      const size_t rb = (size_t)((ym - 1) * 64) * NPAD;
      if (u0) s += bf2f(U[rb + (size_t)xm * NPAD + (4 * 5 + xr) * 64 + b]);
      if (u1) s += bf2f(U[rb + (size_t)(xm - 1) * NPAD + (4 * 5 + 4) * 64 + b]);
    }
    t_lds[xg * 16 + xi][b] = s * (1.0f / 6.0f);
  }
  __syncthreads();
  unsigned short* db = resbf + (((size_t)n * 258 + (y + 1)) * 264) * 64;
  for (int xi = 0; xi < 16; ++xi) {
    const int x = xg * 16 + xi;
    db[(size_t)(xt * 64 + x + 1) * 64 + b] = f2bf(t_lds[x][b]);
  }
}

extern "C" void kernel_launch(void* const* d_in, const int* in_sizes, int n_in,
                              void* d_out, int out_size, void* d_ws, size_t ws_size,
                              hipStream_t stream) {
  const float* ms   = (const float*)d_in[0];
  const float* pan  = (const float*)d_in[1];
  const float* pan2 = (const float*)d_in[2];
  const float* Wq   = (const float*)d_in[3];
  const float* bq   = (const float*)d_in[4];
  const float* Wk   = (const float*)d_in[5];
  const float* bk   = (const float*)d_in[6];
  const float* Wv   = (const float*)d_in[7];
  const float* bv   = (const float*)d_in[8];
  const float* Wr   = (const float*)d_in[9];
  const float* br   = (const float*)d_in[10];
  float* out = (float*)d_out;

  float* ws = (float*)d_ws;
  const size_t SZ_QP  = (size_t)NB * CI * QP2;
  const size_t SZ_K   = (size_t)NB * CI * HK * HK;
  const size_t SZ_WN  = (size_t)NB * 64 * 64 * LL;
  const size_t SZ_VPT = (size_t)NB * NPAD * 256 / 2;
  const size_t SZ_KP  = (size_t)NB * 50 * 256 * 32;
  const size_t SZ_PS  = (size_t)NB * CI * 66 * 72;
  const size_t SZ_WI4 = 4 * 23040;
  const size_t SZ_U1F = (size_t)4096 * NPAD / 2;
  const size_t SZ_UAF = (size_t)NB * SZ_U1F;

  float* q_pad   = ws;
  float* k_fea   = q_pad + SZ_QP;
  float* v_fea   = k_fea + SZ_K;
  float* wnbf_f  = v_fea + SZ_K;
  float* vptbf_f = wnbf_f + SZ_WN / 2;
  float* kp      = vptbf_f + SZ_VPT;
  float* norms   = kp + SZ_KP;
  float* kscale  = norms + NB * LL;
  float* wimgf   = kscale + 64;
  float* msrci_f = wimgf + SZ_WI4;
  float* p2rci_f = msrci_f + SZ_PS;
  float* tail    = p2rci_f + SZ_PS;

  unsigned short* qhi  = (unsigned short*)q_pad;
  unsigned short* qlo  = qhi + (size_t)NB * QP2 * 64;
  unsigned short* khi  = (unsigned short*)kp;
  unsigned short* klo  = khi + (size_t)NB * 50 * 256 * 32;
  unsigned short* wimg  = (unsigned short*)wimgf;
  unsigned short* wimgk = wimg;
  unsigned short* wimgv = wimg + (size_t)1 * 18 * 64 * 40;
  unsigned short* wimgq = wimg + (size_t)2 * 18 * 64 * 40;
  unsigned short* wimgr = wimg + (size_t)3 * 18 * 64 * 40;
  unsigned short* msrci = (unsigned short*)msrci_f;
  unsigned short* p2rci = (unsigned short*)p2rci_f;
  unsigned short* wnbf  = (unsigned short*)wnbf_f;
  unsigned short* vptbf = (unsigned short*)vptbf_f;
  unsigned short* panbf = (unsigned short*)tail;
  unsigned short* U     = (unsigned short*)tail;
  unsigned short* resbf = (unsigned short*)q_pad;

  const size_t base_elems = (size_t)(tail - ws);
  const bool batched = ws_size >= (base_elems + SZ_UAF) * sizeof(float);

  // weight prep (k,v,q,r in one launch)
  wtrans_mfma4<<<dim3(18, 4), 256, 0, stream>>>(Wk, Wv, Wq, Wr, wimg);

  // pad inputs to rci bf16
  pad_rci_s2<<<dim3(66, NB, 2), 256, 0, stream>>>(ms, msrci, pan2, p2rci);
  pad_rci<<<dim3(4, 258, NB), 256, 0, stream>>>(pan, panbf);

  // feature convs: ALL MFMA bf16
  conv3m<<<dim3(1, 32, NB), 256, 0, stream>>>(p2rci, wimgk, bk, k_fea, HK * HK, HK,
                                              72 * 64, (long long)66 * 72 * 64);
  conv3m<<<dim3(1, 32, NB), 256, 0, stream>>>(msrci, wimgv, bv, v_fea, HK * HK, HK,
                                              72 * 64, (long long)66 * 72 * 64);
  conv3mq<<<dim3(4, 128, NB), 256, 0, stream>>>(panbf, wimgq, bq, qhi, qlo);
  qz<<<dim3(NB), 256, 0, stream>>>(qhi, qlo);

  // k-patch max norm -> scale
  knorm_kernel<<<dim3(LL, NB), 64, 0, stream>>>(k_fea, norms);
  kscale_kernel<<<NB, 256, 0, stream>>>(norms, kscale);

  // K im2col hi/lo (kscale folded)
  kp_gather2<<<dim3(25, 2, NB), 256, 0, stream>>>(k_fea, kscale, khi, klo);

  // fused QK MFMA (K-split) + softmax -> bf16 wn
  qk_fused<<<dim3(64, NB), 512, 0, stream>>>(qhi, qlo, khi, klo, wnbf);

  // resbf borders (aliases q hi/lo; dead after qk_fused)
  rbz<<<dim3(NB), 256, 0, stream>>>(resbf);

  // v patch bf16 transposed matrix
  vpt_gather<<<dim3(NPAD / 4, NB), 256, 0, stream>>>(v_fea, vptbf);

  // PV MFMA (LDS, bf16 U) + conv-transpose gather
  if (batched) {
    pv_mfma<<<dim3(64, 13, NB), 256, 0, stream>>>(wnbf, vptbf, U);
    u_scatter<<<dim3(4, HQ, NB), 256, 0, stream>>>(U, resbf, 0);
  } else {
    for (int n = 0; n < NB; ++n) {
      pv_mfma<<<dim3(64, 13, 1), 256, 0, stream>>>(wnbf + (size_t)n * 4096 * 256,
                                                   vptbf + (size_t)n * NPAD * 256, U);
      u_scatter<<<dim3(4, HQ, 1), 256, 0, stream>>>(U, resbf, n);
    }
  }

  // final conv (MFMA bf16, 2 rows/block) -> d_out fp32
  conv3m<<<dim3(4, 128, NB), 256, 0, stream>>>(resbf, wimgr, br, out, HQ * HQ, HQ,
                                               264 * 64, (long long)258 * 264 * 64);
}